// Round 4
// baseline (79.443 us; speedup 1.0000x reference)
//
#include <hip/hip_runtime.h>
#include <math.h>

#define B_     16
#define NX_    8192
#define C_     128
#define K1_    17          // kx + 1 retained frequencies
#define NC_    64          // n-chunks for forward kernel (1 slot each)
#define NSP_   128         // n-span per chunk/block

typedef float v2f __attribute__((ext_vector_type(2)));

// Workspace layout (floats):
//   Gpart : [B][NC][K1][2(cos-sum, sin-sum)][C]   (17.8 MB)
//   Acoef : [B][K1][C] float2 (ar, ai)            (0.28 MB)
#define GPART_F ((size_t)B_ * NC_ * K1_ * 2 * C_)
#define SSTR_   35          // reduce-slot stride in float4 (bank spread)

// ---------------------------------------------------------------------------
// Forward truncated DFT. Block = (b, chunk of 128 n).
// Lane owns 4 channels; half-waves carry n-parity (2 n per wave-step).
// Trig in LDS as {c,c,s,s} float4 -> 17 ds_read_b128 per 2n x 128ch.
// ---------------------------------------------------------------------------
__global__ __launch_bounds__(256) void k_fwd(const float* __restrict__ x,
                                             float* __restrict__ ws) {
    __shared__ float4 smem[64 * SSTR_];   // 35840 B >= trig (2176 float4)

    float* gpart = ws;
    const int b = blockIdx.y;
    const int chunk = blockIdx.x;
    const int t = threadIdx.x;
    const int jq = t & 31;              // channel quad: 4*jq .. 4*jq+3
    const int sub = (t >> 5) & 1;       // n parity within wave step
    const int h = t >> 6;               // wave id (n-subrange)
    const int n0 = chunk * NSP_;

    // build trig table: (nn, k) -> {c, c, s, s}
    for (int idx = t; idx < NSP_ * K1_; idx += 256) {
        int nn = idx / K1_;
        int k = idx - nn * K1_;
        int m = (k * (n0 + nn)) & (NX_ - 1);
        float rev = (float)m * (1.0f / (float)NX_);    // exact
        float c = __builtin_amdgcn_cosf(rev);          // cos(2*pi*rev)
        float s = __builtin_amdgcn_sinf(rev);          // sin(2*pi*rev)
        smem[idx] = make_float4(c, c, s, s);
    }
    __syncthreads();

    v2f grA[K1_], grB[K1_], gsA[K1_], gsB[K1_];
#pragma unroll
    for (int k = 0; k < K1_; ++k) {
        grA[k] = (v2f)(0.f); grB[k] = (v2f)(0.f);
        gsA[k] = (v2f)(0.f); gsB[k] = (v2f)(0.f);
    }

    const float4* xp = (const float4*)(x + ((size_t)b * NX_ + n0 + h * 32 + sub) * C_) + jq;
    const float4* tl = smem + (h * 32 + sub) * K1_;
#pragma unroll 2
    for (int stp = 0; stp < 16; ++stp) {
        float4 xv = xp[(size_t)stp * 64];              // +2 rows (coalesced 512B/half-wave)
        const float4* tr = tl + stp * 2 * K1_;         // uniform per half-wave
        v2f xA = {xv.x, xv.y}, xB = {xv.z, xv.w};
#pragma unroll
        for (int k = 0; k < K1_; ++k) {
            float4 tt = tr[k];
            v2f cc = {tt.x, tt.y}, ss = {tt.z, tt.w};
            grA[k] = __builtin_elementwise_fma(xA, cc, grA[k]);
            grB[k] = __builtin_elementwise_fma(xB, cc, grB[k]);
            gsA[k] = __builtin_elementwise_fma(xA, ss, gsA[k]);
            gsB[k] = __builtin_elementwise_fma(xB, ss, gsB[k]);
        }
    }

    // fold the two n-parity lanes (l <-> l^32)
#pragma unroll
    for (int k = 0; k < K1_; ++k) {
        grA[k].x += __shfl_xor(grA[k].x, 32); grA[k].y += __shfl_xor(grA[k].y, 32);
        grB[k].x += __shfl_xor(grB[k].x, 32); grB[k].y += __shfl_xor(grB[k].y, 32);
        gsA[k].x += __shfl_xor(gsA[k].x, 32); gsA[k].y += __shfl_xor(gsA[k].y, 32);
        gsB[k].x += __shfl_xor(gsB[k].x, 32); gsB[k].y += __shfl_xor(gsB[k].y, 32);
    }

    __syncthreads();    // all waves done reading trig; reuse LDS for reduction
    if (h >= 2 && sub == 0) {
        float4* p = (float4*)smem + ((h - 2) * 32 + jq) * SSTR_;
#pragma unroll
        for (int k = 0; k < K1_; ++k) {
            p[2 * k]     = make_float4(grA[k].x, grA[k].y, grB[k].x, grB[k].y);
            p[2 * k + 1] = make_float4(gsA[k].x, gsA[k].y, gsB[k].x, gsB[k].y);
        }
    }
    __syncthreads();
    if (h < 2 && sub == 0) {
        const float4* p = (const float4*)smem + (h * 32 + jq) * SSTR_;
#pragma unroll
        for (int k = 0; k < K1_; ++k) {
            float4 a = p[2 * k], s4 = p[2 * k + 1];
            grA[k].x += a.x;  grA[k].y += a.y;  grB[k].x += a.z;  grB[k].y += a.w;
            gsA[k].x += s4.x; gsA[k].y += s4.y; gsB[k].x += s4.z; gsB[k].y += s4.w;
        }
    }
    __syncthreads();
    if (h == 1 && sub == 0) {
        float4* p = (float4*)smem + jq * SSTR_;
#pragma unroll
        for (int k = 0; k < K1_; ++k) {
            p[2 * k]     = make_float4(grA[k].x, grA[k].y, grB[k].x, grB[k].y);
            p[2 * k + 1] = make_float4(gsA[k].x, gsA[k].y, gsB[k].x, gsB[k].y);
        }
    }
    __syncthreads();
    if (h == 0 && sub == 0) {
        const float4* p = (const float4*)smem + jq * SSTR_;
        float* gp = gpart + (((size_t)b * NC_ + chunk) * K1_) * 2 * C_;
#pragma unroll
        for (int k = 0; k < K1_; ++k) {
            float4 a = p[2 * k], s4 = p[2 * k + 1];
            float4 vr = make_float4(grA[k].x + a.x,  grA[k].y + a.y,
                                    grB[k].x + a.z,  grB[k].y + a.w);
            float4 vs = make_float4(gsA[k].x + s4.x, gsA[k].y + s4.y,
                                    gsB[k].x + s4.z, gsB[k].y + s4.w);
            ((float4*)(gp + (k * 2 + 0) * C_))[jq] = vr;
            ((float4*)(gp + (k * 2 + 1) * C_))[jq] = vs;
        }
    }
}

// ---------------------------------------------------------------------------
// Reduce NC slots, apply complex weight matmul (G = gr - i*gs),
// fold irfft scaling into coefs. 256 threads: slots and jj both split in two.
// ---------------------------------------------------------------------------
__global__ __launch_bounds__(256) void k_mix(const float* __restrict__ wr_g,
                                             const float* __restrict__ wi_g,
                                             float* __restrict__ ws) {
    const int k = blockIdx.x;
    const int b = blockIdx.y;
    const int t = threadIdx.x;
    const int i = t & 127;
    const int h = t >> 7;

    const float* gpart = ws;
    float2* acoef = (float2*)(ws + GPART_F);

    __shared__ float grs[C_], gss[C_], tr_[C_], ti_[C_];

    float gr = 0.f, gs = 0.f;
    const float* base = gpart + ((size_t)b * NC_) * K1_ * 2 * C_ + (size_t)k * 2 * C_;
    for (int s = h * 32; s < h * 32 + 32; ++s) {
        const float* gp = base + (size_t)s * (K1_ * 2 * C_);
        gr += gp[i];
        gs += gp[C_ + i];
    }
    if (h) { tr_[i] = gr; ti_[i] = gs; }
    __syncthreads();
    if (!h) { grs[i] = gr + tr_[i]; gss[i] = gs + ti_[i]; }
    __syncthreads();

    // H = W * (gr - i*gs):  hr = wr*gr + wi*gs ; hi = wi*gr - wr*gs
    float hr = 0.f, hi = 0.f;
    const float* wrp = wr_g + ((size_t)k * C_ + i) * C_;
    const float* wip = wi_g + ((size_t)k * C_ + i) * C_;
    for (int jj = h * 64; jj < h * 64 + 64; ++jj) {
        float wr = wrp[jj], wi = wip[jj];
        float a = grs[jj], c = gss[jj];
        hr = fmaf(wr, a, hr); hr = fmaf( wi, c, hr);
        hi = fmaf(wi, a, hi); hi = fmaf(-wr, c, hi);
    }
    __syncthreads();
    if (h) { tr_[i] = hr; ti_[i] = hi; }
    __syncthreads();
    if (!h) {
        hr += tr_[i]; hi += ti_[i];
        // out[n] = sum_k c_k*(hr*cos - hi*sin) -> ar = c*hr, ai = -c*hi
        float cf = (k == 0 ? 1.0f : 2.0f) / (float)NX_;
        acoef[((size_t)b * K1_ + k) * C_ + i] = make_float2(cf * hr, -cf * hi);
    }
}

// ---------------------------------------------------------------------------
// Inverse: out[b,n,i] = sum_k ar[k,i]*cos + ai[k,i]*sin.
// Lane owns 4 channels; 2 n per wave-step; trig {c,c,s,s} in LDS.
// ---------------------------------------------------------------------------
__global__ __launch_bounds__(256) void k_inv(float* __restrict__ out,
                                             const float* __restrict__ ws) {
    __shared__ float4 smem[NSP_ * K1_];   // 34816 B

    const float4* acoef4 = (const float4*)(ws + GPART_F);
    const int b = blockIdx.y;
    const int t = threadIdx.x;
    const int jq = t & 31;              // channel quad
    const int sub = (t >> 5) & 1;       // n parity
    const int h = t >> 6;               // wave id
    const int n0 = blockIdx.x * NSP_;

    for (int idx = t; idx < NSP_ * K1_; idx += 256) {
        int nn = idx / K1_;
        int k = idx - nn * K1_;
        int m = (k * (n0 + nn)) & (NX_ - 1);
        float rev = (float)m * (1.0f / (float)NX_);
        float c = __builtin_amdgcn_cosf(rev);
        float s = __builtin_amdgcn_sinf(rev);
        smem[idx] = make_float4(c, c, s, s);
    }

    v2f arA[K1_], aiA[K1_], arB[K1_], aiB[K1_];
#pragma unroll
    for (int k = 0; k < K1_; ++k) {
        const float4* row = acoef4 + ((size_t)b * K1_ + k) * (C_ / 2);
        float4 p0 = row[2 * jq], p1 = row[2 * jq + 1];
        arA[k] = (v2f){p0.x, p0.z}; aiA[k] = (v2f){p0.y, p0.w};
        arB[k] = (v2f){p1.x, p1.z}; aiB[k] = (v2f){p1.y, p1.w};
    }
    __syncthreads();

    const float4* tl = smem + (h * 32 + sub) * K1_;
    float* op = out + ((size_t)b * NX_ + n0 + h * 32 + sub) * C_ + 4 * jq;
#pragma unroll 2
    for (int stp = 0; stp < 16; ++stp) {
        const float4* tr = tl + stp * 2 * K1_;         // uniform per half-wave
        v2f oA = (v2f)(0.f), oB = (v2f)(0.f);
#pragma unroll
        for (int k = 0; k < K1_; ++k) {
            float4 tt = tr[k];
            v2f cc = {tt.x, tt.y}, ss = {tt.z, tt.w};
            oA = __builtin_elementwise_fma(arA[k], cc, oA);
            oA = __builtin_elementwise_fma(aiA[k], ss, oA);
            oB = __builtin_elementwise_fma(arB[k], cc, oB);
            oB = __builtin_elementwise_fma(aiB[k], ss, oB);
        }
        *(float4*)(op + (size_t)stp * 2 * C_) = make_float4(oA.x, oA.y, oB.x, oB.y);
    }
}

extern "C" void kernel_launch(void* const* d_in, const int* in_sizes, int n_in,
                              void* d_out, int out_size, void* d_ws, size_t ws_size,
                              hipStream_t stream) {
    const float* x  = (const float*)d_in[0];   // (B, NX, C) fp32
    const float* wr = (const float*)d_in[1];   // (K1, C, C) fp32
    const float* wi = (const float*)d_in[2];   // (K1, C, C) fp32
    float* out = (float*)d_out;                // (B, NX, C) fp32
    float* ws  = (float*)d_ws;                 // ~18.1 MB used

    k_fwd<<<dim3(NC_, B_), 256, 0, stream>>>(x, ws);
    k_mix<<<dim3(K1_, B_), 256, 0, stream>>>(wr, wi, ws);
    k_inv<<<dim3(NX_ / NSP_, B_), 256, 0, stream>>>(out, ws);
}

// Round 5
// 63.613 us; speedup vs baseline: 1.2489x; 1.2489x over previous
//
#include <hip/hip_runtime.h>
#include <math.h>

#define B_     16
#define NX_    8192
#define C_     128
#define K1_    17          // kx + 1 retained frequencies
#define NC_    64          // n-chunks for forward kernel (1 slot each)
#define NSP_   128         // n-span per chunk/block

typedef float v2f __attribute__((ext_vector_type(2)));

// Workspace layout (floats):
//   Gpart : [B][NC][K1][2(cos-sum, sin-sum)][C]   (17.8 MB)
//   Acoef : [B][K1][C] float2 (ar, ai)            (0.28 MB)
#define GPART_F ((size_t)B_ * NC_ * K1_ * 2 * C_)

// ---------------------------------------------------------------------------
// Forward truncated DFT. Block = (b, chunk of 128 n). Lane owns 2 channels.
// Trig stored ONCE in LDS as {c,s}; {c,c}/{s,s} built by register broadcast
// (folds into v_pk_fma op_sel). 17 ds_read_b64 per n instead of 34.
// ---------------------------------------------------------------------------
__global__ __launch_bounds__(256) void k_fwd(const float* __restrict__ x,
                                             float* __restrict__ ws) {
    __shared__ float smem[8960];        // trig: 4352 floats; reduction: 8960

    float* gpart = ws;
    const int b = blockIdx.y;
    const int chunk = blockIdx.x;
    const int t = threadIdx.x;
    const int j2 = t & 63;              // channel pair 2*j2, 2*j2+1
    const int h = t >> 6;               // wave id (n-subrange)
    const int n0 = chunk * NSP_;

    // trig table: (nn, k) -> {c, s}
    {
        float2* s2 = (float2*)smem;
        for (int idx = t; idx < NSP_ * K1_; idx += 256) {
            int nn = idx / K1_;
            int k = idx - nn * K1_;
            int m = (k * (n0 + nn)) & (NX_ - 1);
            float rev = (float)m * (1.0f / (float)NX_);   // exact
            s2[idx] = make_float2(__builtin_amdgcn_cosf(rev),
                                  __builtin_amdgcn_sinf(rev));
        }
    }
    __syncthreads();

    v2f gr[K1_], gs[K1_];
#pragma unroll
    for (int k = 0; k < K1_; ++k) { gr[k] = (v2f)(0.f); gs[k] = (v2f)(0.f); }

    const v2f* xp = (const v2f*)(x + ((size_t)b * NX_ + n0 + h * 32) * C_) + j2;
    const float2* tl = (const float2*)smem + (size_t)h * 32 * K1_;
#pragma unroll 4
    for (int nn = 0; nn < 32; ++nn) {
        v2f xv = xp[(size_t)nn * 64];                   // coalesced 512B/wave
        const float2* tr = tl + nn * K1_;               // wave-uniform LDS row
#pragma unroll
        for (int k = 0; k < K1_; ++k) {
            float2 tt = tr[k];
            v2f cc = {tt.x, tt.x};                      // op_sel broadcast
            v2f ss = {tt.y, tt.y};
            gr[k] = __builtin_elementwise_fma(xv, cc, gr[k]);
            gs[k] = __builtin_elementwise_fma(xv, ss, gs[k]);
        }
    }

    // two-round reduction across h-groups (reuses trig LDS space)
    // rows of 35 float2 (stride 70 floats -> banks spread)
    float2* red = (float2*)smem;
    __syncthreads();
    if (h >= 2) {
        float2* p = red + ((h - 2) * 64 + j2) * 35;
#pragma unroll
        for (int k = 0; k < K1_; ++k) {
            p[2 * k]     = make_float2(gr[k].x, gr[k].y);
            p[2 * k + 1] = make_float2(gs[k].x, gs[k].y);
        }
    }
    __syncthreads();
    if (h < 2) {
        const float2* p = red + (h * 64 + j2) * 35;
#pragma unroll
        for (int k = 0; k < K1_; ++k) {
            float2 a = p[2 * k], c = p[2 * k + 1];
            gr[k].x += a.x; gr[k].y += a.y;
            gs[k].x += c.x; gs[k].y += c.y;
        }
    }
    __syncthreads();
    if (h == 1) {
        float2* p = red + j2 * 35;
#pragma unroll
        for (int k = 0; k < K1_; ++k) {
            p[2 * k]     = make_float2(gr[k].x, gr[k].y);
            p[2 * k + 1] = make_float2(gs[k].x, gs[k].y);
        }
    }
    __syncthreads();
    if (h == 0) {
        const float2* p = red + j2 * 35;
        float* gp = gpart + (((size_t)b * NC_ + chunk) * K1_) * 2 * C_;
#pragma unroll
        for (int k = 0; k < K1_; ++k) {
            float2 a = p[2 * k], c = p[2 * k + 1];
            gr[k].x += a.x; gr[k].y += a.y;
            gs[k].x += c.x; gs[k].y += c.y;
            ((v2f*)(gp + (k * 2 + 0) * C_))[j2] = gr[k];
            ((v2f*)(gp + (k * 2 + 1) * C_))[j2] = gs[k];
        }
    }
}

// ---------------------------------------------------------------------------
// Reduce NC slots, apply complex weight matmul (G = gr - i*gs),
// fold irfft scaling into coefs. 256 threads: slots and jj both split in two.
// ---------------------------------------------------------------------------
__global__ __launch_bounds__(256) void k_mix(const float* __restrict__ wr_g,
                                             const float* __restrict__ wi_g,
                                             float* __restrict__ ws) {
    const int k = blockIdx.x;
    const int b = blockIdx.y;
    const int t = threadIdx.x;
    const int i = t & 127;
    const int h = t >> 7;

    const float* gpart = ws;
    float2* acoef = (float2*)(ws + GPART_F);

    __shared__ float grs[C_], gss[C_], tr_[C_], ti_[C_];

    float gr = 0.f, gs = 0.f;
    const float* base = gpart + ((size_t)b * NC_) * K1_ * 2 * C_ + (size_t)k * 2 * C_;
#pragma unroll
    for (int s = 0; s < 32; ++s) {                      // all loads in flight
        const float* gp = base + (size_t)(h * 32 + s) * (K1_ * 2 * C_);
        gr += gp[i];
        gs += gp[C_ + i];
    }
    if (h) { tr_[i] = gr; ti_[i] = gs; }
    __syncthreads();
    if (!h) { grs[i] = gr + tr_[i]; gss[i] = gs + ti_[i]; }
    __syncthreads();

    // H = W * (gr - i*gs):  hr = wr*gr + wi*gs ; hi = wi*gr - wr*gs
    float hr = 0.f, hi = 0.f;
    const float* wrp = wr_g + ((size_t)k * C_ + i) * C_;
    const float* wip = wi_g + ((size_t)k * C_ + i) * C_;
#pragma unroll 8
    for (int jj = h * 64; jj < h * 64 + 64; ++jj) {
        float wr = wrp[jj], wi = wip[jj];
        float a = grs[jj], c = gss[jj];
        hr = fmaf(wr, a, hr); hr = fmaf( wi, c, hr);
        hi = fmaf(wi, a, hi); hi = fmaf(-wr, c, hi);
    }
    __syncthreads();
    if (h) { tr_[i] = hr; ti_[i] = hi; }
    __syncthreads();
    if (!h) {
        hr += tr_[i]; hi += ti_[i];
        // out[n] = sum_k c_k*(hr*cos - hi*sin) -> ar = c*hr, ai = -c*hi
        float cf = (k == 0 ? 1.0f : 2.0f) / (float)NX_;
        acoef[((size_t)b * K1_ + k) * C_ + i] = make_float2(cf * hr, -cf * hi);
    }
}

// ---------------------------------------------------------------------------
// Inverse: out[b,n,i] = sum_k ar[k,i]*cos + ai[k,i]*sin.
// Lane owns 2 channels; trig {c,s} once in LDS; broadcast via op_sel.
// ---------------------------------------------------------------------------
__global__ __launch_bounds__(256) void k_inv(float* __restrict__ out,
                                             const float* __restrict__ ws) {
    __shared__ float2 smem[NSP_ * K1_];   // 17408 B

    const float4* acoef4 = (const float4*)(ws + GPART_F);
    const int b = blockIdx.y;
    const int t = threadIdx.x;
    const int jp = t & 63;          // channel pair 2*jp, 2*jp+1
    const int h = t >> 6;           // wave id (n-subrange)
    const int n0 = blockIdx.x * NSP_;

    for (int idx = t; idx < NSP_ * K1_; idx += 256) {
        int nn = idx / K1_;
        int k = idx - nn * K1_;
        int m = (k * (n0 + nn)) & (NX_ - 1);
        float rev = (float)m * (1.0f / (float)NX_);
        smem[idx] = make_float2(__builtin_amdgcn_cosf(rev),
                                __builtin_amdgcn_sinf(rev));
    }

    v2f arP[K1_], aiP[K1_];
#pragma unroll
    for (int k = 0; k < K1_; ++k) {
        float4 a = acoef4[((size_t)b * K1_ + k) * (C_ / 2) + jp];
        arP[k] = (v2f){a.x, a.z};
        aiP[k] = (v2f){a.y, a.w};
    }
    __syncthreads();

    const float2* tl = smem + (size_t)h * 32 * K1_;
    float* op = out + ((size_t)b * NX_ + n0 + h * 32) * C_;
#pragma unroll 4
    for (int nn = 0; nn < 32; ++nn) {
        const float2* tr = tl + nn * K1_;
        v2f o = (v2f)(0.f);
#pragma unroll
        for (int k = 0; k < K1_; ++k) {
            float2 tt = tr[k];
            v2f cc = {tt.x, tt.x};
            v2f ss = {tt.y, tt.y};
            o = __builtin_elementwise_fma(arP[k], cc, o);
            o = __builtin_elementwise_fma(aiP[k], ss, o);
        }
        ((v2f*)(op + (size_t)nn * C_))[jp] = o;
    }
}

extern "C" void kernel_launch(void* const* d_in, const int* in_sizes, int n_in,
                              void* d_out, int out_size, void* d_ws, size_t ws_size,
                              hipStream_t stream) {
    const float* x  = (const float*)d_in[0];   // (B, NX, C) fp32
    const float* wr = (const float*)d_in[1];   // (K1, C, C) fp32
    const float* wi = (const float*)d_in[2];   // (K1, C, C) fp32
    float* out = (float*)d_out;                // (B, NX, C) fp32
    float* ws  = (float*)d_ws;                 // ~18.1 MB used

    k_fwd<<<dim3(NC_, B_), 256, 0, stream>>>(x, ws);
    k_mix<<<dim3(K1_, B_), 256, 0, stream>>>(wr, wi, ws);
    k_inv<<<dim3(NX_ / NSP_, B_), 256, 0, stream>>>(out, ws);
}

// Round 6
// 53.628 us; speedup vs baseline: 1.4814x; 1.1862x over previous
//
#include <hip/hip_runtime.h>
#include <math.h>

#define B_     16
#define NX_    8192
#define C_     128
#define K1_    17          // kx + 1 retained frequencies
#define NC_    64          // chunks; chunk owns 64 lo-rows + their hi partners
#define NH_    4096        // NX/2

typedef float v2f __attribute__((ext_vector_type(2)));

// Workspace layout (floats):
//   Gpart : [B][K1][2(cos,sin)][NC][C]   k-major  (17.8 MB)
//   Acoef : [B][K1][C] float2 (ar, ai)            (0.28 MB)
#define GPART_F ((size_t)B_ * K1_ * 2 * NC_ * C_)

// ---------------------------------------------------------------------------
// Forward truncated DFT with n <-> N-n conjugate-symmetry folding.
// Block = (b, chunk c). Lane owns 2 channels. chunk c covers nlo = c*64+i,
// i in [0,64), plus hi partners N-nlo. n=0 self-paired; n=4096 extra in c==0.
// Per pair: 2 global b64 loads, 17 ds_read_b64, 34 pk-FMA (= 17 FMA/n).
// ---------------------------------------------------------------------------
__global__ __launch_bounds__(256) void k_fwd(const float* __restrict__ x,
                                             float* __restrict__ ws) {
    __shared__ float smem[8960];        // trig: 2176 floats; reduction: 8960

    float* gpart = ws;
    const int b = blockIdx.y;
    const int c = blockIdx.x;
    const int t = threadIdx.x;
    const int j2 = t & 63;              // channel pair 2*j2, 2*j2+1
    const int h = t >> 6;               // wave id
    const int i0 = c * 64;

    // trig table: (i, k) -> {cos, sin}(2*pi*k*(i0+i)/NX)
    {
        float2* tg = (float2*)smem;
        for (int idx = t; idx < 64 * K1_; idx += 256) {
            int i = idx / K1_;
            int k = idx - i * K1_;
            int m = (k * (i0 + i)) & (NX_ - 1);
            float rev = (float)m * (1.0f / (float)NX_);   // exact
            tg[idx] = make_float2(__builtin_amdgcn_cosf(rev),
                                  __builtin_amdgcn_sinf(rev));
        }
    }
    __syncthreads();

    v2f gr[K1_], gs[K1_];
#pragma unroll
    for (int k = 0; k < K1_; ++k) { gr[k] = (v2f)(0.f); gs[k] = (v2f)(0.f); }

    const size_t xb = (size_t)b * NX_ * C_;
    const float2* tl = (const float2*)smem + (size_t)h * 16 * K1_;
#pragma unroll 4
    for (int s = 0; s < 16; ++s) {
        const int i = h * 16 + s;
        const int nlo = i0 + i;
        v2f xlo = *(const v2f*)(x + xb + (size_t)nlo * C_ + 2 * j2);
        v2f xhi = (v2f)(0.f);
        if (nlo > 0)                      // n=0 is self-paired
            xhi = *(const v2f*)(x + xb + (size_t)(NX_ - nlo) * C_ + 2 * j2);
        v2f xp = xlo + xhi;
        v2f xm = xlo - xhi;
        const float2* tr = tl + s * K1_;                // wave-uniform LDS row
#pragma unroll
        for (int k = 0; k < K1_; ++k) {
            float2 tt = tr[k];
            v2f cc = {tt.x, tt.x};
            v2f ss = {tt.y, tt.y};
            gr[k] = __builtin_elementwise_fma(xp, cc, gr[k]);
            gs[k] = __builtin_elementwise_fma(xm, ss, gs[k]);
        }
    }

    // two-round reduction across h-groups (reuses trig LDS space)
    float2* red = (float2*)smem;
    __syncthreads();
    if (h >= 2) {
        float2* p = red + ((h - 2) * 64 + j2) * 35;
#pragma unroll
        for (int k = 0; k < K1_; ++k) {
            p[2 * k]     = make_float2(gr[k].x, gr[k].y);
            p[2 * k + 1] = make_float2(gs[k].x, gs[k].y);
        }
    }
    __syncthreads();
    if (h < 2) {
        const float2* p = red + (h * 64 + j2) * 35;
#pragma unroll
        for (int k = 0; k < K1_; ++k) {
            float2 a = p[2 * k], cc = p[2 * k + 1];
            gr[k].x += a.x;  gr[k].y += a.y;
            gs[k].x += cc.x; gs[k].y += cc.y;
        }
    }
    __syncthreads();
    if (h == 1) {
        float2* p = red + j2 * 35;
#pragma unroll
        for (int k = 0; k < K1_; ++k) {
            p[2 * k]     = make_float2(gr[k].x, gr[k].y);
            p[2 * k + 1] = make_float2(gs[k].x, gs[k].y);
        }
    }
    __syncthreads();
    if (h == 0) {
        const float2* p = red + j2 * 35;
        // n = NH (=4096) straggler: cos(pi*k) = (-1)^k, sin = 0 — chunk 0 only
        v2f x4 = (v2f)(0.f);
        if (c == 0)
            x4 = *(const v2f*)(x + xb + (size_t)NH_ * C_ + 2 * j2);
#pragma unroll
        for (int k = 0; k < K1_; ++k) {
            float2 a = p[2 * k], cc = p[2 * k + 1];
            gr[k].x += a.x;  gr[k].y += a.y;
            gs[k].x += cc.x; gs[k].y += cc.y;
            gr[k] += (k & 1) ? -x4 : x4;
            float* gpR = gpart + ((((size_t)b * K1_ + k) * 2 + 0) * NC_ + c) * C_;
            float* gpS = gpart + ((((size_t)b * K1_ + k) * 2 + 1) * NC_ + c) * C_;
            ((v2f*)gpR)[j2] = gr[k];
            ((v2f*)gpS)[j2] = gs[k];
        }
    }
}

// ---------------------------------------------------------------------------
// Reduce NC slots (contiguous streams in k-major layout), apply complex
// weight matmul (G = gr - i*gs), fold irfft scaling into coefs.
// ---------------------------------------------------------------------------
__global__ __launch_bounds__(256) void k_mix(const float* __restrict__ wr_g,
                                             const float* __restrict__ wi_g,
                                             float* __restrict__ ws) {
    const int k = blockIdx.x;
    const int b = blockIdx.y;
    const int t = threadIdx.x;
    const int i = t & 127;
    const int h = t >> 7;

    const float* gpart = ws;
    float2* acoef = (float2*)(ws + GPART_F);

    __shared__ float grs[C_], gss[C_], tr_[C_], ti_[C_];

    const float* baseR = gpart + (((size_t)b * K1_ + k) * 2 + 0) * ((size_t)NC_ * C_);
    const float* baseS = gpart + (((size_t)b * K1_ + k) * 2 + 1) * ((size_t)NC_ * C_);
    float gr = 0.f, gs = 0.f;
#pragma unroll
    for (int s = 0; s < 32; ++s) {                      // contiguous streaming
        gr += baseR[(size_t)(h * 32 + s) * C_ + i];
        gs += baseS[(size_t)(h * 32 + s) * C_ + i];
    }
    if (h) { tr_[i] = gr; ti_[i] = gs; }
    __syncthreads();
    if (!h) { grs[i] = gr + tr_[i]; gss[i] = gs + ti_[i]; }
    __syncthreads();

    // H = W * (gr - i*gs):  hr = wr*gr + wi*gs ; hi = wi*gr - wr*gs
    float hr = 0.f, hi = 0.f;
    const float* wrp = wr_g + ((size_t)k * C_ + i) * C_;
    const float* wip = wi_g + ((size_t)k * C_ + i) * C_;
#pragma unroll 8
    for (int jj = h * 64; jj < h * 64 + 64; ++jj) {
        float wr = wrp[jj], wi = wip[jj];
        float a = grs[jj], cc = gss[jj];
        hr = fmaf(wr, a, hr); hr = fmaf( wi, cc, hr);
        hi = fmaf(wi, a, hi); hi = fmaf(-wr, cc, hi);
    }
    __syncthreads();
    if (h) { tr_[i] = hr; ti_[i] = hi; }
    __syncthreads();
    if (!h) {
        hr += tr_[i]; hi += ti_[i];
        // out[n] = sum_k c_k*(hr*cos - hi*sin) -> ar = c*hr, ai = -c*hi
        float cf = (k == 0 ? 1.0f : 2.0f) / (float)NX_;
        acoef[((size_t)b * K1_ + k) * C_ + i] = make_float2(cf * hr, -cf * hi);
    }
}

// ---------------------------------------------------------------------------
// Inverse with symmetry: S1 = sum ar*cos, S2 = sum ai*sin;
// out[nlo] = S1+S2, out[NX-nlo] = S1-S2. n=0 single; n=4096 extra in c==0.
// ---------------------------------------------------------------------------
__global__ __launch_bounds__(256) void k_inv(float* __restrict__ out,
                                             const float* __restrict__ ws) {
    __shared__ float2 smem[64 * K1_];   // 8704 B

    const float4* acoef4 = (const float4*)(ws + GPART_F);
    const int b = blockIdx.y;
    const int c = blockIdx.x;
    const int t = threadIdx.x;
    const int jp = t & 63;          // channel pair 2*jp, 2*jp+1
    const int h = t >> 6;           // wave id
    const int i0 = c * 64;

    for (int idx = t; idx < 64 * K1_; idx += 256) {
        int i = idx / K1_;
        int k = idx - i * K1_;
        int m = (k * (i0 + i)) & (NX_ - 1);
        float rev = (float)m * (1.0f / (float)NX_);
        smem[idx] = make_float2(__builtin_amdgcn_cosf(rev),
                                __builtin_amdgcn_sinf(rev));
    }

    v2f arP[K1_], aiP[K1_];
#pragma unroll
    for (int k = 0; k < K1_; ++k) {
        float4 a = acoef4[((size_t)b * K1_ + k) * (C_ / 2) + jp];
        arP[k] = (v2f){a.x, a.z};
        aiP[k] = (v2f){a.y, a.w};
    }
    __syncthreads();

    const size_t ob = (size_t)b * NX_ * C_;
    const float2* tl = smem + (size_t)h * 16 * K1_;
#pragma unroll 4
    for (int s = 0; s < 16; ++s) {
        const int nlo = i0 + h * 16 + s;
        const float2* tr = tl + s * K1_;                // wave-uniform LDS row
        v2f S1 = (v2f)(0.f), S2 = (v2f)(0.f);
#pragma unroll
        for (int k = 0; k < K1_; ++k) {
            float2 tt = tr[k];
            v2f cc = {tt.x, tt.x};
            v2f ss = {tt.y, tt.y};
            S1 = __builtin_elementwise_fma(arP[k], cc, S1);
            S2 = __builtin_elementwise_fma(aiP[k], ss, S2);
        }
        *(v2f*)(out + ob + (size_t)nlo * C_ + 2 * jp) = S1 + S2;
        if (nlo > 0)
            *(v2f*)(out + ob + (size_t)(NX_ - nlo) * C_ + 2 * jp) = S1 - S2;
    }

    if (c == 0 && h == 0) {         // n = 4096: out = sum_k ar*(-1)^k
        v2f o = (v2f)(0.f);
#pragma unroll
        for (int k = 0; k < K1_; ++k) o += (k & 1) ? -arP[k] : arP[k];
        *(v2f*)(out + ob + (size_t)NH_ * C_ + 2 * jp) = o;
    }
}

extern "C" void kernel_launch(void* const* d_in, const int* in_sizes, int n_in,
                              void* d_out, int out_size, void* d_ws, size_t ws_size,
                              hipStream_t stream) {
    const float* x  = (const float*)d_in[0];   // (B, NX, C) fp32
    const float* wr = (const float*)d_in[1];   // (K1, C, C) fp32
    const float* wi = (const float*)d_in[2];   // (K1, C, C) fp32
    float* out = (float*)d_out;                // (B, NX, C) fp32
    float* ws  = (float*)d_ws;                 // ~18.1 MB used

    k_fwd<<<dim3(NC_, B_), 256, 0, stream>>>(x, ws);
    k_mix<<<dim3(K1_, B_), 256, 0, stream>>>(wr, wi, ws);
    k_inv<<<dim3(NC_, B_), 256, 0, stream>>>(out, ws);
}

// Round 7
// 52.905 us; speedup vs baseline: 1.5016x; 1.0137x over previous
//
#include <hip/hip_runtime.h>
#include <math.h>

#define B_     16
#define NX_    8192
#define C_     128
#define K1_    17          // kx + 1 retained frequencies
#define KP_    18          // k padded (k=17 is a zero column)
#define NC_    64          // chunks; chunk owns 64 lo-rows + their hi partners
#define NH_    4096        // NX/2

typedef float v2f __attribute__((ext_vector_type(2)));
typedef float v4f __attribute__((ext_vector_type(4)));

// Workspace layout (floats):
//   Gpart : [B][K1][2(cos,sin)][NC][C]   k-major  (17.8 MB)
//   Acoef : [B][K1][C] float2 (ar, ai)            (0.28 MB)
#define GPART_F ((size_t)B_ * K1_ * 2 * NC_ * C_)

// ---------------------------------------------------------------------------
// Forward truncated DFT, conjugate-symmetry folded, k-half sub-split.
// Block = (b, chunk c) of 64 pairs. Lane = (jq: channel quad, sub: k-half).
// Each lane: 4 channels, 9 k's (k = sub*9+kk, k=17 dead). Per pair:
// 2 global b128 loads (broadcast across sub halves), 9 ds_read_b64
// (2 broadcast groups/instr), 36 pk-FMA.
// ---------------------------------------------------------------------------
__global__ __launch_bounds__(256) void k_fwd(const float* __restrict__ x,
                                             float* __restrict__ ws) {
    __shared__ v4f smem[2 * 64 * 19];   // 38912 B; trig uses first 576 v4f

    float* gpart = ws;
    const int b = blockIdx.y;
    const int c = blockIdx.x;
    const int t = threadIdx.x;
    const int jq  = t & 31;             // channel quad: 4*jq .. 4*jq+3
    const int sub = (t >> 5) & 1;       // k-half
    const int w   = t >> 6;             // wave id
    const int i0  = c * 64;

    // trig table: (i, k) -> {cos, sin}(2*pi*k*(i0+i)/NX), k in [0,18)
    {
        float2* tg = (float2*)smem;
        for (int idx = t; idx < 64 * KP_; idx += 256) {
            int i = idx / KP_;
            int k = idx - i * KP_;
            float2 v = make_float2(0.f, 0.f);
            if (k < K1_) {
                int m = (k * (i0 + i)) & (NX_ - 1);
                float rev = (float)m * (1.0f / (float)NX_);   // exact
                v = make_float2(__builtin_amdgcn_cosf(rev),
                                __builtin_amdgcn_sinf(rev));
            }
            tg[idx] = v;
        }
    }
    __syncthreads();

    v4f gr[9], gs[9];
#pragma unroll
    for (int kk = 0; kk < 9; ++kk) { gr[kk] = (v4f)(0.f); gs[kk] = (v4f)(0.f); }

    const size_t xb = (size_t)b * NX_ * C_;
    const int ibase = w * 16;           // this wave's local pair range
    const float2* tp = (const float2*)smem + (size_t)ibase * KP_ + sub * 9;
    const float* xlo_p = x + xb + (size_t)(i0 + ibase) * C_ + 4 * jq;
    const float* xhi_p = x + xb + (size_t)(NX_ - (i0 + ibase)) * C_ + 4 * jq;

#pragma unroll 4
    for (int s = 0; s < 16; ++s) {
        const int nlo = i0 + ibase + s;
        v4f xlo = *(const v4f*)(xlo_p + (size_t)s * C_);
        v4f xhi = (v4f)(0.f);
        if (nlo > 0)                    // n=0 self-paired (wave-uniform branch)
            xhi = *(const v4f*)(xhi_p - (size_t)s * C_);
        v4f xp = xlo + xhi;
        v4f xm = xlo - xhi;
        const float2* tr = tp + (size_t)s * KP_;
#pragma unroll
        for (int kk = 0; kk < 9; ++kk) {
            float2 tt = tr[kk];         // per-lane k = sub*9+kk
            gr[kk] = __builtin_elementwise_fma(xp, (v4f)(tt.x), gr[kk]);
            gs[kk] = __builtin_elementwise_fma(xm, (v4f)(tt.y), gs[kk]);
        }
    }

    // n = 4096 straggler: cos(pi*k) = (-1)^k, sin = 0 — chunk 0, wave 0 only
    if (c == 0 && w == 0) {
        v4f x4 = *(const v4f*)(x + xb + (size_t)NH_ * C_ + 4 * jq);
#pragma unroll
        for (int kk = 0; kk < 9; ++kk) {
            int k = sub * 9 + kk;
            gr[kk] += (k & 1) ? -x4 : x4;
        }
    }

    // two-round cross-wave reduction (reuses trig LDS; stride 19 v4f)
    const int lid = t & 63;
    __syncthreads();
    if (w >= 2) {
        v4f* p = smem + ((size_t)(w - 2) * 64 + lid) * 19;
#pragma unroll
        for (int kk = 0; kk < 9; ++kk) { p[2 * kk] = gr[kk]; p[2 * kk + 1] = gs[kk]; }
    }
    __syncthreads();
    if (w < 2) {
        const v4f* p = smem + ((size_t)w * 64 + lid) * 19;
#pragma unroll
        for (int kk = 0; kk < 9; ++kk) { gr[kk] += p[2 * kk]; gs[kk] += p[2 * kk + 1]; }
    }
    __syncthreads();
    if (w == 1) {
        v4f* p = smem + (size_t)lid * 19;
#pragma unroll
        for (int kk = 0; kk < 9; ++kk) { p[2 * kk] = gr[kk]; p[2 * kk + 1] = gs[kk]; }
    }
    __syncthreads();
    if (w == 0) {
        const v4f* p = smem + (size_t)lid * 19;
#pragma unroll
        for (int kk = 0; kk < 9; ++kk) {
            gr[kk] += p[2 * kk];
            gs[kk] += p[2 * kk + 1];
            int k = sub * 9 + kk;
            if (k < K1_) {
                float* gpR = gpart + ((((size_t)b * K1_ + k) * 2 + 0) * NC_ + c) * C_ + 4 * jq;
                float* gpS = gpart + ((((size_t)b * K1_ + k) * 2 + 1) * NC_ + c) * C_ + 4 * jq;
                *(v4f*)gpR = gr[kk];
                *(v4f*)gpS = gs[kk];
            }
        }
    }
}

// ---------------------------------------------------------------------------
// Reduce NC slots + complex weight matmul, 1024 threads for latency hiding.
// Phase A: 4-way slot-split coalesced streaming reduction.
// Phase C: 8-way jj-split matmul; LDS combine. G = gr - i*gs.
// ---------------------------------------------------------------------------
__global__ __launch_bounds__(1024) void k_mix(const float* __restrict__ wr_g,
                                              const float* __restrict__ wi_g,
                                              float* __restrict__ ws) {
    const int k = blockIdx.x;
    const int b = blockIdx.y;
    const int t = threadIdx.x;

    const float* gpart = ws;
    float2* acoef = (float2*)(ws + GPART_F);

    __shared__ float part[8][C_];    // [sh*2+ri][ch]
    __shared__ float gsum[2][C_];    // reduced G (cos, sin parts)
    __shared__ float hp[16][C_];     // [q*2+ri][i]

    {   // phase A: each thread streams 16 contiguous slot-rows
        const int ch = t & 127, ri = (t >> 7) & 1, sh = t >> 8;   // sh 0..3
        const float* base = gpart
            + (((size_t)b * K1_ + k) * 2 + ri) * ((size_t)NC_ * C_) + ch;
        float g = 0.f;
#pragma unroll
        for (int s = 0; s < 16; ++s) g += base[(size_t)(sh * 16 + s) * C_];
        part[sh * 2 + ri][ch] = g;
    }
    __syncthreads();
    if (t < 256) {
        const int ch = t & 127, ri = t >> 7;
        gsum[ri][ch] = part[ri][ch] + part[2 + ri][ch]
                     + part[4 + ri][ch] + part[6 + ri][ch];
    }
    __syncthreads();

    {   // phase C: H = W * (gr - i*gs), jj split 8 ways
        const int i = t & 127, q = t >> 7;   // q 0..7
        float hr = 0.f, hi = 0.f;
        const float* wrp = wr_g + ((size_t)k * C_ + i) * C_;
        const float* wip = wi_g + ((size_t)k * C_ + i) * C_;
#pragma unroll
        for (int jjj = 0; jjj < 16; ++jjj) {
            int jj = q * 16 + jjj;
            float wr = wrp[jj], wi = wip[jj];
            float a = gsum[0][jj], cc = gsum[1][jj];
            hr = fmaf(wr, a, hr); hr = fmaf( wi, cc, hr);
            hi = fmaf(wi, a, hi); hi = fmaf(-wr, cc, hi);
        }
        hp[q * 2 + 0][i] = hr;
        hp[q * 2 + 1][i] = hi;
    }
    __syncthreads();
    if (t < 128) {
        const int i = t;
        float hr = 0.f, hi = 0.f;
#pragma unroll
        for (int q = 0; q < 8; ++q) { hr += hp[q * 2][i]; hi += hp[q * 2 + 1][i]; }
        // out[n] = sum_k c_k*(hr*cos - hi*sin) -> ar = c*hr, ai = -c*hi
        float cf = (k == 0 ? 1.0f : 2.0f) / (float)NX_;
        acoef[((size_t)b * K1_ + k) * C_ + i] = make_float2(cf * hr, -cf * hi);
    }
}

// ---------------------------------------------------------------------------
// Inverse with symmetry: S1 = sum ar*cos, S2 = sum ai*sin;
// out[nlo] = S1+S2, out[NX-nlo] = S1-S2. n=0 single; n=4096 extra in c==0.
// ---------------------------------------------------------------------------
__global__ __launch_bounds__(256) void k_inv(float* __restrict__ out,
                                             const float* __restrict__ ws) {
    __shared__ float2 smem[64 * K1_];   // 8704 B

    const float4* acoef4 = (const float4*)(ws + GPART_F);
    const int b = blockIdx.y;
    const int c = blockIdx.x;
    const int t = threadIdx.x;
    const int jp = t & 63;          // channel pair 2*jp, 2*jp+1
    const int h = t >> 6;           // wave id
    const int i0 = c * 64;

    for (int idx = t; idx < 64 * K1_; idx += 256) {
        int i = idx / K1_;
        int k = idx - i * K1_;
        int m = (k * (i0 + i)) & (NX_ - 1);
        float rev = (float)m * (1.0f / (float)NX_);
        smem[idx] = make_float2(__builtin_amdgcn_cosf(rev),
                                __builtin_amdgcn_sinf(rev));
    }

    v2f arP[K1_], aiP[K1_];
#pragma unroll
    for (int k = 0; k < K1_; ++k) {
        float4 a = acoef4[((size_t)b * K1_ + k) * (C_ / 2) + jp];
        arP[k] = (v2f){a.x, a.z};
        aiP[k] = (v2f){a.y, a.w};
    }
    __syncthreads();

    const size_t ob = (size_t)b * NX_ * C_;
    const float2* tl = smem + (size_t)h * 16 * K1_;
#pragma unroll 4
    for (int s = 0; s < 16; ++s) {
        const int nlo = i0 + h * 16 + s;
        const float2* tr = tl + s * K1_;                // wave-uniform LDS row
        v2f S1 = (v2f)(0.f), S2 = (v2f)(0.f);
#pragma unroll
        for (int k = 0; k < K1_; ++k) {
            float2 tt = tr[k];
            v2f cc = {tt.x, tt.x};
            v2f ss = {tt.y, tt.y};
            S1 = __builtin_elementwise_fma(arP[k], cc, S1);
            S2 = __builtin_elementwise_fma(aiP[k], ss, S2);
        }
        *(v2f*)(out + ob + (size_t)nlo * C_ + 2 * jp) = S1 + S2;
        if (nlo > 0)
            *(v2f*)(out + ob + (size_t)(NX_ - nlo) * C_ + 2 * jp) = S1 - S2;
    }

    if (c == 0 && h == 0) {         // n = 4096: out = sum_k ar*(-1)^k
        v2f o = (v2f)(0.f);
#pragma unroll
        for (int k = 0; k < K1_; ++k) o += (k & 1) ? -arP[k] : arP[k];
        *(v2f*)(out + ob + (size_t)NH_ * C_ + 2 * jp) = o;
    }
}

extern "C" void kernel_launch(void* const* d_in, const int* in_sizes, int n_in,
                              void* d_out, int out_size, void* d_ws, size_t ws_size,
                              hipStream_t stream) {
    const float* x  = (const float*)d_in[0];   // (B, NX, C) fp32
    const float* wr = (const float*)d_in[1];   // (K1, C, C) fp32
    const float* wi = (const float*)d_in[2];   // (K1, C, C) fp32
    float* out = (float*)d_out;                // (B, NX, C) fp32
    float* ws  = (float*)d_ws;                 // ~18.1 MB used

    k_fwd<<<dim3(NC_, B_), 256, 0, stream>>>(x, ws);
    k_mix<<<dim3(K1_, B_), 1024, 0, stream>>>(wr, wi, ws);
    k_inv<<<dim3(NC_, B_), 256, 0, stream>>>(out, ws);
}

// Round 8
// 51.755 us; speedup vs baseline: 1.5350x; 1.0222x over previous
//
#include <hip/hip_runtime.h>
#include <math.h>

#define B_     16
#define NX_    8192
#define C_     128
#define K1_    17          // kx + 1 retained frequencies
#define KP_    18          // padded k slots (one dead)
#define NC_    64          // chunks; chunk owns 64 lo-rows + hi partners (+NX/2)
#define NH_    4096        // NX/2

typedef float v2f __attribute__((ext_vector_type(2)));
typedef float v4f __attribute__((ext_vector_type(4)));

// Workspace layout (floats):
//   Gpart : [B][K1][2(cos,sin)][NC][C]   k-major  (17.8 MB)
//   Acoef : [B][K1][C] float2 (ar, ai)            (0.28 MB)
#define GPART_F ((size_t)B_ * K1_ * 2 * NC_ * C_)

// ---------------------------------------------------------------------------
// Forward truncated DFT, folded over n <-> n+NX/2 (both streams ascending):
//   G_k = sum_{n<NH} (x[n] + (-1)^k x[n+NH]) e^{-i th_kn}
// Lane = (jq: channel quad, sub: k-parity half). sub=0 owns even k (9),
// sub=1 odd k (8 + 1 dead). Per pair: 2 global b128, 1 v4f-fma fold,
// 9 ds_read_b64 (2 bcast groups), 36 pk-FMA.
// ---------------------------------------------------------------------------
__global__ __launch_bounds__(256) void k_fwd(const float* __restrict__ x,
                                             float* __restrict__ ws) {
    __shared__ v4f smem[2 * 64 * 19];   // 38912 B; trig uses first 576 v4f

    float* gpart = ws;
    const int b = blockIdx.y;
    const int c = blockIdx.x;
    const int t = threadIdx.x;
    const int jq  = t & 31;             // channel quad: 4*jq .. 4*jq+3
    const int sub = (t >> 5) & 1;       // k-parity half (0: even, 1: odd)
    const int w   = t >> 6;             // wave id
    const int i0  = c * 64;

    // trig table: (i, p) -> {cos, sin}(2*pi*k*(i0+i)/NX)
    // p<9: k=2p (even); 9<=p<17: k=2(p-9)+1 (odd); p=17: zero pad
    {
        float2* tg = (float2*)smem;
        for (int idx = t; idx < 64 * KP_; idx += 256) {
            int i = idx / KP_;
            int p = idx - i * KP_;
            float2 v = make_float2(0.f, 0.f);
            if (p < K1_) {
                int k = (p < 9) ? 2 * p : 2 * (p - 9) + 1;
                int m = (k * (i0 + i)) & (NX_ - 1);
                float rev = (float)m * (1.0f / (float)NX_);   // exact
                v = make_float2(__builtin_amdgcn_cosf(rev),
                                __builtin_amdgcn_sinf(rev));
            }
            tg[idx] = v;
        }
    }
    __syncthreads();

    v4f gr[9], gs[9];
#pragma unroll
    for (int kk = 0; kk < 9; ++kk) { gr[kk] = (v4f)(0.f); gs[kk] = (v4f)(0.f); }

    const size_t xb = (size_t)b * NX_ * C_;
    const int ibase = w * 16;           // this wave's local pair range
    const float sg = sub ? -1.f : 1.f;  // (-1)^k for this lane's k-parity
    const float2* tp = (const float2*)smem + (size_t)ibase * KP_ + sub * 9;
    const float* xlo_p = x + xb + (size_t)(i0 + ibase) * C_ + 4 * jq;
    const float* xhi_p = xlo_p + (size_t)NH_ * C_;

#pragma unroll 4
    for (int s = 0; s < 16; ++s) {
        v4f xlo = *(const v4f*)(xlo_p + (size_t)s * C_);    // ascending stream
        v4f xhi = *(const v4f*)(xhi_p + (size_t)s * C_);    // ascending stream
        v4f xs = __builtin_elementwise_fma(xhi, (v4f)(sg), xlo);
        const float2* tr = tp + (size_t)s * KP_;
#pragma unroll
        for (int kk = 0; kk < 9; ++kk) {
            float2 tt = tr[kk];         // per-lane k
            gr[kk] = __builtin_elementwise_fma(xs, (v4f)(tt.x), gr[kk]);
            gs[kk] = __builtin_elementwise_fma(xs, (v4f)(tt.y), gs[kk]);
        }
    }

    // two-round cross-wave reduction (reuses trig LDS; stride 19 v4f)
    const int lid = t & 63;
    __syncthreads();
    if (w >= 2) {
        v4f* p = smem + ((size_t)(w - 2) * 64 + lid) * 19;
#pragma unroll
        for (int kk = 0; kk < 9; ++kk) { p[2 * kk] = gr[kk]; p[2 * kk + 1] = gs[kk]; }
    }
    __syncthreads();
    if (w < 2) {
        const v4f* p = smem + ((size_t)w * 64 + lid) * 19;
#pragma unroll
        for (int kk = 0; kk < 9; ++kk) { gr[kk] += p[2 * kk]; gs[kk] += p[2 * kk + 1]; }
    }
    __syncthreads();
    if (w == 1) {
        v4f* p = smem + (size_t)lid * 19;
#pragma unroll
        for (int kk = 0; kk < 9; ++kk) { p[2 * kk] = gr[kk]; p[2 * kk + 1] = gs[kk]; }
    }
    __syncthreads();
    if (w == 0) {
        const v4f* p = smem + (size_t)lid * 19;
#pragma unroll
        for (int kk = 0; kk < 9; ++kk) {
            gr[kk] += p[2 * kk];
            gs[kk] += p[2 * kk + 1];
            if (sub == 0 || kk < 8) {
                int k = sub ? 2 * kk + 1 : 2 * kk;
                float* gpR = gpart + ((((size_t)b * K1_ + k) * 2 + 0) * NC_ + c) * C_ + 4 * jq;
                float* gpS = gpart + ((((size_t)b * K1_ + k) * 2 + 1) * NC_ + c) * C_ + 4 * jq;
                *(v4f*)gpR = gr[kk];
                *(v4f*)gpS = gs[kk];
            }
        }
    }
}

// ---------------------------------------------------------------------------
// Reduce NC slots + complex weight matmul, 1024 threads for latency hiding.
// Phase A: 4-way slot-split coalesced streaming reduction.
// Phase C: 8-way jj-split matmul; LDS combine. G = gr - i*gs.
// ---------------------------------------------------------------------------
__global__ __launch_bounds__(1024) void k_mix(const float* __restrict__ wr_g,
                                              const float* __restrict__ wi_g,
                                              float* __restrict__ ws) {
    const int k = blockIdx.x;
    const int b = blockIdx.y;
    const int t = threadIdx.x;

    const float* gpart = ws;
    float2* acoef = (float2*)(ws + GPART_F);

    __shared__ float part[8][C_];    // [sh*2+ri][ch]
    __shared__ float gsum[2][C_];    // reduced G (cos, sin parts)
    __shared__ float hp[16][C_];     // [q*2+ri][i]

    {   // phase A: each thread streams 16 contiguous slot-rows
        const int ch = t & 127, ri = (t >> 7) & 1, sh = t >> 8;   // sh 0..3
        const float* base = gpart
            + (((size_t)b * K1_ + k) * 2 + ri) * ((size_t)NC_ * C_) + ch;
        float g = 0.f;
#pragma unroll
        for (int s = 0; s < 16; ++s) g += base[(size_t)(sh * 16 + s) * C_];
        part[sh * 2 + ri][ch] = g;
    }
    __syncthreads();
    if (t < 256) {
        const int ch = t & 127, ri = t >> 7;
        gsum[ri][ch] = part[ri][ch] + part[2 + ri][ch]
                     + part[4 + ri][ch] + part[6 + ri][ch];
    }
    __syncthreads();

    {   // phase C: H = W * (gr - i*gs), jj split 8 ways
        const int i = t & 127, q = t >> 7;   // q 0..7
        float hr = 0.f, hi = 0.f;
        const float* wrp = wr_g + ((size_t)k * C_ + i) * C_;
        const float* wip = wi_g + ((size_t)k * C_ + i) * C_;
#pragma unroll
        for (int jjj = 0; jjj < 16; ++jjj) {
            int jj = q * 16 + jjj;
            float wr = wrp[jj], wi = wip[jj];
            float a = gsum[0][jj], cc = gsum[1][jj];
            hr = fmaf(wr, a, hr); hr = fmaf( wi, cc, hr);
            hi = fmaf(wi, a, hi); hi = fmaf(-wr, cc, hi);
        }
        hp[q * 2 + 0][i] = hr;
        hp[q * 2 + 1][i] = hi;
    }
    __syncthreads();
    if (t < 128) {
        const int i = t;
        float hr = 0.f, hi = 0.f;
#pragma unroll
        for (int q = 0; q < 8; ++q) { hr += hp[q * 2][i]; hi += hp[q * 2 + 1][i]; }
        // out[n] = sum_k c_k*(hr*cos - hi*sin) -> ar = c*hr, ai = -c*hi
        float cf = (k == 0 ? 1.0f : 2.0f) / (float)NX_;
        acoef[((size_t)b * K1_ + k) * C_ + i] = make_float2(cf * hr, -cf * hi);
    }
}

// ---------------------------------------------------------------------------
// Inverse, folded over n <-> n+NH: Se = even-k terms, So = odd-k terms;
// out[n] = Se+So, out[n+NH] = Se-So. Both write streams ascending.
// ---------------------------------------------------------------------------
__global__ __launch_bounds__(256) void k_inv(float* __restrict__ out,
                                             const float* __restrict__ ws) {
    __shared__ float2 smem[64 * K1_];   // 8704 B

    const float4* acoef4 = (const float4*)(ws + GPART_F);
    const int b = blockIdx.y;
    const int c = blockIdx.x;
    const int t = threadIdx.x;
    const int jp = t & 63;          // channel pair 2*jp, 2*jp+1
    const int h = t >> 6;           // wave id
    const int i0 = c * 64;

    for (int idx = t; idx < 64 * K1_; idx += 256) {
        int i = idx / K1_;
        int k = idx - i * K1_;
        int m = (k * (i0 + i)) & (NX_ - 1);
        float rev = (float)m * (1.0f / (float)NX_);
        smem[idx] = make_float2(__builtin_amdgcn_cosf(rev),
                                __builtin_amdgcn_sinf(rev));
    }

    v2f arP[K1_], aiP[K1_];
#pragma unroll
    for (int k = 0; k < K1_; ++k) {
        float4 a = acoef4[((size_t)b * K1_ + k) * (C_ / 2) + jp];
        arP[k] = (v2f){a.x, a.z};
        aiP[k] = (v2f){a.y, a.w};
    }
    __syncthreads();

    const size_t ob = (size_t)b * NX_ * C_;
    const float2* tl = smem + (size_t)h * 16 * K1_;
    float* olo = out + ob + (size_t)(i0 + h * 16) * C_ + 2 * jp;
    float* ohi = olo + (size_t)NH_ * C_;
#pragma unroll 4
    for (int s = 0; s < 16; ++s) {
        const float2* tr = tl + s * K1_;                // wave-uniform LDS row
        v2f Se = (v2f)(0.f), So = (v2f)(0.f);
#pragma unroll
        for (int k = 0; k < K1_; ++k) {
            float2 tt = tr[k];
            v2f cc = {tt.x, tt.x};
            v2f ss = {tt.y, tt.y};
            if ((k & 1) == 0) {
                Se = __builtin_elementwise_fma(arP[k], cc, Se);
                Se = __builtin_elementwise_fma(aiP[k], ss, Se);
            } else {
                So = __builtin_elementwise_fma(arP[k], cc, So);
                So = __builtin_elementwise_fma(aiP[k], ss, So);
            }
        }
        *(v2f*)(olo + (size_t)s * C_) = Se + So;        // ascending stream
        *(v2f*)(ohi + (size_t)s * C_) = Se - So;        // ascending stream
    }
}

extern "C" void kernel_launch(void* const* d_in, const int* in_sizes, int n_in,
                              void* d_out, int out_size, void* d_ws, size_t ws_size,
                              hipStream_t stream) {
    const float* x  = (const float*)d_in[0];   // (B, NX, C) fp32
    const float* wr = (const float*)d_in[1];   // (K1, C, C) fp32
    const float* wi = (const float*)d_in[2];   // (K1, C, C) fp32
    float* out = (float*)d_out;                // (B, NX, C) fp32
    float* ws  = (float*)d_ws;                 // ~18.1 MB used

    k_fwd<<<dim3(NC_, B_), 256, 0, stream>>>(x, ws);
    k_mix<<<dim3(K1_, B_), 1024, 0, stream>>>(wr, wi, ws);
    k_inv<<<dim3(NC_, B_), 256, 0, stream>>>(out, ws);
}

// Round 9
// 51.623 us; speedup vs baseline: 1.5389x; 1.0026x over previous
//
#include <hip/hip_runtime.h>
#include <math.h>

#define B_     16
#define NX_    8192
#define C_     128
#define K1_    17          // kx + 1 retained frequencies
#define QW_    20          // padded trig-row width in float2 (160 B, 16B-aligned halves)
#define NC_    64          // chunks; chunk owns 64 lo-rows + hi partners (+NX/2)
#define NH_    4096        // NX/2

typedef float v2f __attribute__((ext_vector_type(2)));
typedef float v4f __attribute__((ext_vector_type(4)));

// Workspace layout (floats):
//   Gpart : [B][K1][2(cos,sin)][NC][C]  k-major   (17.8 MB)
//   Acoef : [B][K1][C] float2 (ar, ai)            (0.28 MB)
//   TrigG : [NC][64][2*QW_]  parity-major rows    (0.64 MB)
#define GPART_F  ((size_t)B_ * K1_ * 2 * NC_ * C_)
#define ACOEF_F  ((size_t)B_ * K1_ * C_ * 2)
#define TRIG_OFF (GPART_F + ACOEF_F)

// trig row (float2 index q): q<9 -> even k=2q ; q==9 pad ; 10<=q<18 -> odd
// k=2(q-10)+1 ; q>=18 pad. Row = 40 floats = 160 B; halves at 0 B and 80 B.

// ---------------------------------------------------------------------------
// Forward truncated DFT, folded over n <-> n+NX/2:
//   G_k = sum_{n<NH} (x[n] + (-1)^k x[n+NH]) e^{-i th_kn}
// Lane = (jq: channel quad, sub: k-parity half). Per n: 2 global b128,
// 4 ds_read_b128 + 1 b64 (parity-major trig), 36 pk-FMA.
// b==0 blocks also dump the trig table to global for k_inv.
// ---------------------------------------------------------------------------
__global__ __launch_bounds__(256) void k_fwd(const float* __restrict__ x,
                                             float* __restrict__ ws) {
    __shared__ v4f smem[2 * 64 * 19];   // 38912 B; trig uses first 10240 B

    float* gpart = ws;
    const int b = blockIdx.y;
    const int c = blockIdx.x;
    const int t = threadIdx.x;
    const int jq  = t & 31;             // channel quad: 4*jq .. 4*jq+3
    const int sub = (t >> 5) & 1;       // k-parity half (0: even, 1: odd)
    const int w   = t >> 6;             // wave id
    const int i0  = c * 64;

    // build trig table (LDS) and dump to global (b==0 only)
    {
        float2* tg  = (float2*)smem;
        float2* tgg = (float2*)(ws + TRIG_OFF) + (size_t)c * (64 * QW_);
        for (int idx = t; idx < 64 * QW_; idx += 256) {
            int i = idx / QW_;
            int q = idx - i * QW_;
            float2 v = make_float2(0.f, 0.f);
            int k = (q < 9) ? (2 * q) : ((q >= 10 && q < 18) ? (2 * (q - 10) + 1) : -1);
            if (k >= 0) {
                int m = (k * (i0 + i)) & (NX_ - 1);
                float rev = (float)m * (1.0f / (float)NX_);   // exact
                v = make_float2(__builtin_amdgcn_cosf(rev),
                                __builtin_amdgcn_sinf(rev));
            }
            tg[idx] = v;
            if (b == 0) tgg[idx] = v;
        }
    }
    __syncthreads();

    v4f gr[9], gs[9];
#pragma unroll
    for (int kk = 0; kk < 9; ++kk) { gr[kk] = (v4f)(0.f); gs[kk] = (v4f)(0.f); }

    const size_t xb = (size_t)b * NX_ * C_;
    const int ibase = w * 16;           // this wave's local pair range
    const float sg = sub ? -1.f : 1.f;  // (-1)^k for this lane's k-parity
    const float* tp = (const float*)smem + ((size_t)ibase * QW_ + sub * 10) * 2;
    const float* xlo_p = x + xb + (size_t)(i0 + ibase) * C_ + 4 * jq;
    const float* xhi_p = xlo_p + (size_t)NH_ * C_;

#pragma unroll 4
    for (int s = 0; s < 16; ++s) {
        v4f xlo = *(const v4f*)(xlo_p + (size_t)s * C_);    // ascending stream
        v4f xhi = *(const v4f*)(xhi_p + (size_t)s * C_);    // ascending stream
        v4f xs = __builtin_elementwise_fma(xhi, (v4f)(sg), xlo);
        const float* tr = tp + (size_t)s * (2 * QW_);
        float4 t0 = *(const float4*)(tr + 0);
        float4 t1 = *(const float4*)(tr + 4);
        float4 t2 = *(const float4*)(tr + 8);
        float4 t3 = *(const float4*)(tr + 12);
        float2 t4 = *(const float2*)(tr + 16);
        gr[0] = __builtin_elementwise_fma(xs, (v4f)(t0.x), gr[0]);
        gs[0] = __builtin_elementwise_fma(xs, (v4f)(t0.y), gs[0]);
        gr[1] = __builtin_elementwise_fma(xs, (v4f)(t0.z), gr[1]);
        gs[1] = __builtin_elementwise_fma(xs, (v4f)(t0.w), gs[1]);
        gr[2] = __builtin_elementwise_fma(xs, (v4f)(t1.x), gr[2]);
        gs[2] = __builtin_elementwise_fma(xs, (v4f)(t1.y), gs[2]);
        gr[3] = __builtin_elementwise_fma(xs, (v4f)(t1.z), gr[3]);
        gs[3] = __builtin_elementwise_fma(xs, (v4f)(t1.w), gs[3]);
        gr[4] = __builtin_elementwise_fma(xs, (v4f)(t2.x), gr[4]);
        gs[4] = __builtin_elementwise_fma(xs, (v4f)(t2.y), gs[4]);
        gr[5] = __builtin_elementwise_fma(xs, (v4f)(t2.z), gr[5]);
        gs[5] = __builtin_elementwise_fma(xs, (v4f)(t2.w), gs[5]);
        gr[6] = __builtin_elementwise_fma(xs, (v4f)(t3.x), gr[6]);
        gs[6] = __builtin_elementwise_fma(xs, (v4f)(t3.y), gs[6]);
        gr[7] = __builtin_elementwise_fma(xs, (v4f)(t3.z), gr[7]);
        gs[7] = __builtin_elementwise_fma(xs, (v4f)(t3.w), gs[7]);
        gr[8] = __builtin_elementwise_fma(xs, (v4f)(t4.x), gr[8]);
        gs[8] = __builtin_elementwise_fma(xs, (v4f)(t4.y), gs[8]);
    }

    // two-round cross-wave reduction (reuses trig LDS; stride 19 v4f)
    const int lid = t & 63;
    __syncthreads();
    if (w >= 2) {
        v4f* p = smem + ((size_t)(w - 2) * 64 + lid) * 19;
#pragma unroll
        for (int kk = 0; kk < 9; ++kk) { p[2 * kk] = gr[kk]; p[2 * kk + 1] = gs[kk]; }
    }
    __syncthreads();
    if (w < 2) {
        const v4f* p = smem + ((size_t)w * 64 + lid) * 19;
#pragma unroll
        for (int kk = 0; kk < 9; ++kk) { gr[kk] += p[2 * kk]; gs[kk] += p[2 * kk + 1]; }
    }
    __syncthreads();
    if (w == 1) {
        v4f* p = smem + (size_t)lid * 19;
#pragma unroll
        for (int kk = 0; kk < 9; ++kk) { p[2 * kk] = gr[kk]; p[2 * kk + 1] = gs[kk]; }
    }
    __syncthreads();
    if (w == 0) {
        const v4f* p = smem + (size_t)lid * 19;
#pragma unroll
        for (int kk = 0; kk < 9; ++kk) {
            gr[kk] += p[2 * kk];
            gs[kk] += p[2 * kk + 1];
            if (sub == 0 || kk < 8) {
                int k = sub ? 2 * kk + 1 : 2 * kk;
                float* gpR = gpart + ((((size_t)b * K1_ + k) * 2 + 0) * NC_ + c) * C_ + 4 * jq;
                float* gpS = gpart + ((((size_t)b * K1_ + k) * 2 + 1) * NC_ + c) * C_ + 4 * jq;
                *(v4f*)gpR = gr[kk];
                *(v4f*)gpS = gs[kk];
            }
        }
    }
}

// ---------------------------------------------------------------------------
// Reduce NC slots + complex weight matmul, 1024 threads for latency hiding.
// ---------------------------------------------------------------------------
__global__ __launch_bounds__(1024) void k_mix(const float* __restrict__ wr_g,
                                              const float* __restrict__ wi_g,
                                              float* __restrict__ ws) {
    const int k = blockIdx.x;
    const int b = blockIdx.y;
    const int t = threadIdx.x;

    const float* gpart = ws;
    float2* acoef = (float2*)(ws + GPART_F);

    __shared__ float part[8][C_];    // [sh*2+ri][ch]
    __shared__ float gsum[2][C_];    // reduced G (cos, sin parts)
    __shared__ float hp[16][C_];     // [q*2+ri][i]

    {   // phase A: each thread streams 16 contiguous slot-rows
        const int ch = t & 127, ri = (t >> 7) & 1, sh = t >> 8;   // sh 0..3
        const float* base = gpart
            + (((size_t)b * K1_ + k) * 2 + ri) * ((size_t)NC_ * C_) + ch;
        float g = 0.f;
#pragma unroll
        for (int s = 0; s < 16; ++s) g += base[(size_t)(sh * 16 + s) * C_];
        part[sh * 2 + ri][ch] = g;
    }
    __syncthreads();
    if (t < 256) {
        const int ch = t & 127, ri = t >> 7;
        gsum[ri][ch] = part[ri][ch] + part[2 + ri][ch]
                     + part[4 + ri][ch] + part[6 + ri][ch];
    }
    __syncthreads();

    {   // phase C: H = W * (gr - i*gs), jj split 8 ways
        const int i = t & 127, q = t >> 7;   // q 0..7
        float hr = 0.f, hi = 0.f;
        const float* wrp = wr_g + ((size_t)k * C_ + i) * C_;
        const float* wip = wi_g + ((size_t)k * C_ + i) * C_;
#pragma unroll
        for (int jjj = 0; jjj < 16; ++jjj) {
            int jj = q * 16 + jjj;
            float wr = wrp[jj], wi = wip[jj];
            float a = gsum[0][jj], cc = gsum[1][jj];
            hr = fmaf(wr, a, hr); hr = fmaf( wi, cc, hr);
            hi = fmaf(wi, a, hi); hi = fmaf(-wr, cc, hi);
        }
        hp[q * 2 + 0][i] = hr;
        hp[q * 2 + 1][i] = hi;
    }
    __syncthreads();
    if (t < 128) {
        const int i = t;
        float hr = 0.f, hi = 0.f;
#pragma unroll
        for (int q = 0; q < 8; ++q) { hr += hp[q * 2][i]; hi += hp[q * 2 + 1][i]; }
        // out[n] = sum_k c_k*(hr*cos - hi*sin) -> ar = c*hr, ai = -c*hi
        float cf = (k == 0 ? 1.0f : 2.0f) / (float)NX_;
        acoef[((size_t)b * K1_ + k) * C_ + i] = make_float2(cf * hr, -cf * hi);
    }
}

// ---------------------------------------------------------------------------
// Inverse, folded over n <-> n+NH: Se = even-k terms, So = odd-k terms;
// out[n] = Se+So, out[n+NH] = Se-So. Trig from global via wave-uniform
// (SGPR-based) loads — ZERO LDS, zero DS traffic, no barriers.
// ---------------------------------------------------------------------------
__global__ __launch_bounds__(256) void k_inv(float* __restrict__ out,
                                             const float* __restrict__ ws) {
    const float4* acoef4 = (const float4*)(ws + GPART_F);
    const float* trigg = ws + TRIG_OFF;
    const int b = blockIdx.y;
    const int c = blockIdx.x;
    const int t = threadIdx.x;
    const int jp = t & 63;          // channel pair 2*jp, 2*jp+1
    const int h = __builtin_amdgcn_readfirstlane(t >> 6);   // wave id (uniform)
    const int i0 = c * 64;

    v2f arE[9], aiE[9], arO[8], aiO[8];
#pragma unroll
    for (int q = 0; q < 9; ++q) {
        float4 a = acoef4[((size_t)b * K1_ + 2 * q) * (C_ / 2) + jp];
        arE[q] = (v2f){a.x, a.z}; aiE[q] = (v2f){a.y, a.w};
    }
#pragma unroll
    for (int q = 0; q < 8; ++q) {
        float4 a = acoef4[((size_t)b * K1_ + 2 * q + 1) * (C_ / 2) + jp];
        arO[q] = (v2f){a.x, a.z}; aiO[q] = (v2f){a.y, a.w};
    }

    const float* trow = trigg + ((size_t)c * 64 + h * 16) * (2 * QW_);
    const size_t ob = (size_t)b * NX_ * C_;
    float* olo = out + ob + (size_t)(i0 + h * 16) * C_ + 2 * jp;
    float* ohi = olo + (size_t)NH_ * C_;

#pragma unroll 4
    for (int s = 0; s < 16; ++s) {
        const float* tr = trow + (size_t)s * (2 * QW_);   // wave-uniform row
        float4 e0 = *(const float4*)(tr + 0);
        float4 e1 = *(const float4*)(tr + 4);
        float4 e2 = *(const float4*)(tr + 8);
        float4 e3 = *(const float4*)(tr + 12);
        float2 e4 = *(const float2*)(tr + 16);
        float4 o0 = *(const float4*)(tr + 20);
        float4 o1 = *(const float4*)(tr + 24);
        float4 o2 = *(const float4*)(tr + 28);
        float4 o3 = *(const float4*)(tr + 32);
        v2f Se = (v2f)(0.f), So = (v2f)(0.f);
        Se = __builtin_elementwise_fma(arE[0], (v2f)(e0.x), Se);
        Se = __builtin_elementwise_fma(aiE[0], (v2f)(e0.y), Se);
        Se = __builtin_elementwise_fma(arE[1], (v2f)(e0.z), Se);
        Se = __builtin_elementwise_fma(aiE[1], (v2f)(e0.w), Se);
        Se = __builtin_elementwise_fma(arE[2], (v2f)(e1.x), Se);
        Se = __builtin_elementwise_fma(aiE[2], (v2f)(e1.y), Se);
        Se = __builtin_elementwise_fma(arE[3], (v2f)(e1.z), Se);
        Se = __builtin_elementwise_fma(aiE[3], (v2f)(e1.w), Se);
        Se = __builtin_elementwise_fma(arE[4], (v2f)(e2.x), Se);
        Se = __builtin_elementwise_fma(aiE[4], (v2f)(e2.y), Se);
        Se = __builtin_elementwise_fma(arE[5], (v2f)(e2.z), Se);
        Se = __builtin_elementwise_fma(aiE[5], (v2f)(e2.w), Se);
        Se = __builtin_elementwise_fma(arE[6], (v2f)(e3.x), Se);
        Se = __builtin_elementwise_fma(aiE[6], (v2f)(e3.y), Se);
        Se = __builtin_elementwise_fma(arE[7], (v2f)(e3.z), Se);
        Se = __builtin_elementwise_fma(aiE[7], (v2f)(e3.w), Se);
        Se = __builtin_elementwise_fma(arE[8], (v2f)(e4.x), Se);
        Se = __builtin_elementwise_fma(aiE[8], (v2f)(e4.y), Se);
        So = __builtin_elementwise_fma(arO[0], (v2f)(o0.x), So);
        So = __builtin_elementwise_fma(aiO[0], (v2f)(o0.y), So);
        So = __builtin_elementwise_fma(arO[1], (v2f)(o0.z), So);
        So = __builtin_elementwise_fma(aiO[1], (v2f)(o0.w), So);
        So = __builtin_elementwise_fma(arO[2], (v2f)(o1.x), So);
        So = __builtin_elementwise_fma(aiO[2], (v2f)(o1.y), So);
        So = __builtin_elementwise_fma(arO[3], (v2f)(o1.z), So);
        So = __builtin_elementwise_fma(aiO[3], (v2f)(o1.w), So);
        So = __builtin_elementwise_fma(arO[4], (v2f)(o2.x), So);
        So = __builtin_elementwise_fma(aiO[4], (v2f)(o2.y), So);
        So = __builtin_elementwise_fma(arO[5], (v2f)(o2.z), So);
        So = __builtin_elementwise_fma(aiO[5], (v2f)(o2.w), So);
        So = __builtin_elementwise_fma(arO[6], (v2f)(o3.x), So);
        So = __builtin_elementwise_fma(aiO[6], (v2f)(o3.y), So);
        So = __builtin_elementwise_fma(arO[7], (v2f)(o3.z), So);
        So = __builtin_elementwise_fma(aiO[7], (v2f)(o3.w), So);
        *(v2f*)(olo + (size_t)s * C_) = Se + So;        // ascending stream
        *(v2f*)(ohi + (size_t)s * C_) = Se - So;        // ascending stream
    }
}

extern "C" void kernel_launch(void* const* d_in, const int* in_sizes, int n_in,
                              void* d_out, int out_size, void* d_ws, size_t ws_size,
                              hipStream_t stream) {
    const float* x  = (const float*)d_in[0];   // (B, NX, C) fp32
    const float* wr = (const float*)d_in[1];   // (K1, C, C) fp32
    const float* wi = (const float*)d_in[2];   // (K1, C, C) fp32
    float* out = (float*)d_out;                // (B, NX, C) fp32
    float* ws  = (float*)d_ws;                 // ~18.8 MB used

    k_fwd<<<dim3(NC_, B_), 256, 0, stream>>>(x, ws);
    k_mix<<<dim3(K1_, B_), 1024, 0, stream>>>(wr, wi, ws);
    k_inv<<<dim3(NC_, B_), 256, 0, stream>>>(out, ws);
}